// Round 15
// baseline (916.686 us; speedup 1.0000x reference)
//
#include <hip/hip_runtime.h>
#include <hip/hip_bf16.h>

using f32x4  = __attribute__((ext_vector_type(4))) float;
using bf16x8 = __attribute__((ext_vector_type(8))) short;
using short8 = __attribute__((ext_vector_type(8))) short;
using s16x4  = __attribute__((ext_vector_type(4))) short;

#define DEVINL __device__ __forceinline__

DEVINL short f2bf(float f) {
  unsigned u = __builtin_bit_cast(unsigned, f);
  u += 0x7fffu + ((u >> 16) & 1u);          // RNE
  return (short)(u >> 16);
}

// tanh-approx GELU in sigmoid form: 0.5v(1+tanh(u)) == v/(1+exp(-2u))
DEVINL float gelu_fast(float v) {
  float t = __expf(-1.5957691216057308f * (v + 0.044715f * v * v * v));
  return v * __builtin_amdgcn_rcpf(1.0f + t);
}

#define GLDS16(g, l) __builtin_amdgcn_global_load_lds( \
    (const __attribute__((address_space(1))) void*)(g), \
    (__attribute__((address_space(3))) void*)(l), 16, 0, 0)

// ---------------------------------------------------------------- transpose
__global__ __launch_bounds__(256)
void transpose_bf16(const float* __restrict__ in, short* __restrict__ out, int R, int C) {
  int idx = blockIdx.x * 256 + threadIdx.x;
  if (idx >= R * C) return;
  int c = idx / R, r = idx % R;
  out[idx] = f2bf(in[(size_t)r * C + c]);
}

// ---------------------------------------------------------------- bias expand
__global__ __launch_bounds__(256)
void bias_expand(const float* __restrict__ rpb, float* __restrict__ BIASF) {
  int idx = blockIdx.x * 256 + threadIdx.x;   // 65536
  int head = idx >> 12, n = (idx >> 6) & 63, m = idx & 63;
  int i1 = n >> 3, j1 = n & 7, i2 = m >> 3, j2 = m & 7;
  BIASF[idx] = rpb[((i1 - i2 + 7) * 15 + (j1 - j2 + 7)) * 16 + head];
}

// ---------------------------------------------------------------- LayerNorm
template<int REMAP>
__global__ __launch_bounds__(256)
void ln_kernel(const float* __restrict__ X, const float* __restrict__ gamma,
               const float* __restrict__ beta, short* __restrict__ OUT) {
  const int lane = threadIdx.x & 63;
  const int wid  = threadIdx.x >> 6;
  const int t    = blockIdx.x * 4 + wid;
  const float* xp = X + (size_t)t * 512 + lane * 8;
  float4 a = *(const float4*)xp;
  float4 b = *(const float4*)(xp + 4);
  float s = a.x + a.y + a.z + a.w + b.x + b.y + b.z + b.w;
  float q = a.x*a.x + a.y*a.y + a.z*a.z + a.w*a.w
          + b.x*b.x + b.y*b.y + b.z*b.z + b.w*b.w;
#pragma unroll
  for (int d = 1; d < 64; d <<= 1) { s += __shfl_xor(s, d); q += __shfl_xor(q, d); }
  float mean = s * (1.0f / 512.0f);
  float var  = q * (1.0f / 512.0f) - mean * mean;
  float rstd = rsqrtf(var + 1e-5f);
  float4 g0 = *(const float4*)(gamma + lane * 8);
  float4 g1 = *(const float4*)(gamma + lane * 8 + 4);
  float4 b0 = *(const float4*)(beta + lane * 8);
  float4 b1 = *(const float4*)(beta + lane * 8 + 4);
  short8 o;
  o[0] = f2bf((a.x - mean) * rstd * g0.x + b0.x);
  o[1] = f2bf((a.y - mean) * rstd * g0.y + b0.y);
  o[2] = f2bf((a.z - mean) * rstd * g0.z + b0.z);
  o[3] = f2bf((a.w - mean) * rstd * g0.w + b0.w);
  o[4] = f2bf((b.x - mean) * rstd * g1.x + b1.x);
  o[5] = f2bf((b.y - mean) * rstd * g1.y + b1.y);
  o[6] = f2bf((b.z - mean) * rstd * g1.z + b1.z);
  o[7] = f2bf((b.w - mean) * rstd * g1.w + b1.w);
  size_t orow;
  if (REMAP) {
    int bb = t >> 12, l = t & 4095, hh = l >> 6, ww = l & 63;
    int hs = (hh + 60) & 63, ws2 = (ww + 60) & 63;   // (coord - 4) mod 64
    orow = (size_t)(bb * 64 + (hs >> 3) * 8 + (ws2 >> 3)) * 64 + (hs & 7) * 8 + (ws2 & 7);
  } else {
    orow = (size_t)t;
  }
  *(short8*)(OUT + orow * 512 + lane * 8) = o;
}

// ---------------------------------------------------------------- attention core
__global__ __launch_bounds__(256)
void attn_core(const short* __restrict__ Q, const short* __restrict__ Kb,
               const short* __restrict__ VT, const float* __restrict__ BIASF,
               short* __restrict__ AOUT) {
  __shared__ short P[4][4096];
  const int tid = threadIdx.x, lane = tid & 63, wid = tid >> 6;
  const int lr = lane & 15, lg = lane >> 4;
  const int gw = blockIdx.x * 4 + wid;
  const int win = gw >> 4, head = gw & 15;
  const int wimg = win & 63, wh = wimg >> 3, ww = wimg & 7;
  const size_t qbase = (size_t)win * 64 * 512 + head * 32;
  short* Pb = P[wid];

  bf16x8 aq[4], bk[4];
#pragma unroll
  for (int tm = 0; tm < 4; ++tm) aq[tm] = *(const bf16x8*)(Q  + qbase + (size_t)(tm * 16 + lr) * 512 + lg * 8);
#pragma unroll
  for (int tn = 0; tn < 4; ++tn) bk[tn] = *(const bf16x8*)(Kb + qbase + (size_t)(tn * 16 + lr) * 512 + lg * 8);
  f32x4 sa[4][4] = {};
#pragma unroll
  for (int tm = 0; tm < 4; ++tm)
#pragma unroll
    for (int tn = 0; tn < 4; ++tn)
      sa[tm][tn] = __builtin_amdgcn_mfma_f32_16x16x32_bf16(aq[tm], bk[tn], sa[tm][tn], 0, 0, 0);

  const float* bias_h = BIASF + head * 4096;
  float inv[4][4];
#pragma unroll
  for (int tm = 0; tm < 4; ++tm) {
#pragma unroll
    for (int e = 0; e < 4; ++e) {
      const int n = tm * 16 + lg * 4 + e;
      const int i1 = n >> 3, j1 = n & 7;
      const int rh1 = (wh == 7) ? 1 + (i1 >> 2) : 0;
      const int rw1 = (ww == 7) ? 1 + (j1 >> 2) : 0;
      float v[4];
      float mx = -3.0e38f;
#pragma unroll
      for (int tn = 0; tn < 4; ++tn) {
        const int m = tn * 16 + lr;
        const int mi = (m >> 3), mj = m & 7;
        const int rh2 = (wh == 7) ? 1 + (mi >> 2) : 0;
        const int rw2 = (ww == 7) ? 1 + (mj >> 2) : 0;
        float val = sa[tm][tn][e] + bias_h[n * 64 + m]
                  + ((rh1 != rh2 || rw1 != rw2) ? -100.0f : 0.0f);
        v[tn] = val;
        mx = fmaxf(mx, val);
      }
#pragma unroll
      for (int d = 1; d < 16; d <<= 1) mx = fmaxf(mx, __shfl_xor(mx, d));
      float sum = 0.f;
#pragma unroll
      for (int tn = 0; tn < 4; ++tn) { v[tn] = __expf(v[tn] - mx); sum += v[tn]; }
#pragma unroll
      for (int d = 1; d < 16; d <<= 1) sum += __shfl_xor(sum, d);
      inv[tm][e] = 1.0f / sum;
      const int sw = (n & 7) << 3;
#pragma unroll
      for (int tn = 0; tn < 4; ++tn) Pb[n * 64 + ((tn * 16 + lr) ^ sw)] = f2bf(v[tn]);
    }
  }
  __syncthreads();

  f32x4 oa[4][2] = {};
  const short* vt = VT + (size_t)win * 32768 + head * 2048;
#pragma unroll
  for (int ks = 0; ks < 2; ++ks) {
    bf16x8 pa[4], bv[2];
#pragma unroll
    for (int tm = 0; tm < 4; ++tm) {
      const int r = tm * 16 + lr;
      pa[tm] = *(const bf16x8*)(Pb + r * 64 + ((ks * 32 + lg * 8) ^ ((r & 7) << 3)));
    }
#pragma unroll
    for (int t2 = 0; t2 < 2; ++t2) bv[t2] = *(const bf16x8*)(vt + (t2 * 16 + lr) * 64 + ks * 32 + lg * 8);
#pragma unroll
    for (int tm = 0; tm < 4; ++tm)
#pragma unroll
      for (int t2 = 0; t2 < 2; ++t2)
        oa[tm][t2] = __builtin_amdgcn_mfma_f32_16x16x32_bf16(pa[tm], bv[t2], oa[tm][t2], 0, 0, 0);
  }
#pragma unroll
  for (int tm = 0; tm < 4; ++tm)
#pragma unroll
    for (int t2 = 0; t2 < 2; ++t2)
#pragma unroll
      for (int e = 0; e < 4; ++e) {
        const int n = tm * 16 + lg * 4 + e;
        AOUT[((size_t)win * 64 + n) * 512 + head * 32 + t2 * 16 + lr] = f2bf(oa[tm][t2][e] * inv[tm][e]);
      }
}

// ---------------------------------------------------------------- 128x128 GEMM v5 (m97-simple + fixes)
// R8's proven simple structure: single 16KB LDS buffer, per K-tile
// {GLDS -> __syncthreads -> ds_read frags -> 16 MFMA -> __syncthreads}.
// Compiler manages all waitcnts (m97: implicit wave-level overlap at
// 16 waves/CU captures what source pipelining adds — m114/m99/m100).
// Plus: both-sides LDS swizzle (0 conflicts), XCD-bijective block swizzle
// (A-panel sharers consecutive -> L2 reuse), packed V^T stores.
// 4 waves (2x2), wave tile 64x64, BK=32. Target <=72 arch VGPR.
template<int EPI, int K, int NX>
__global__ __launch_bounds__(256, 2)
void gemm128v5(const short* __restrict__ Aa, const short* __restrict__ Bb,
               const float* __restrict__ bias, const float* __restrict__ resid,
               float* __restrict__ outf, short* __restrict__ outh) {
  __shared__ short L[2][128 * 32];   // [A|B][128 rows][32 cols] = 16KB
  const int tid = threadIdx.x;
  const int lane = tid & 63, wid = tid >> 6;
  const int lr = lane & 15, lg = lane >> 4;
  const int wm = wid >> 1, wn = wid & 1;

  // XCD-aware bijective swizzle (all grids are multiples of 8)
  const int nwg = gridDim.x;
  const int id = blockIdx.x;
  const int id2 = (id & 7) * (nwg >> 3) + (id >> 3);
  const int mt    = (EPI == 1) ? (id2 % NX) : (id2 / NX);
  const int ntile = (EPI == 1) ? (id2 / NX) : (id2 % NX);
  const int m0 = mt * 128, n0 = ntile * 128;

  // staging: thread covers rows r0 and r0+64 of A and B (4 GLDS16/tile)
  const int r0 = tid >> 2;
  const int cdb = (tid & 3) * 16;                                // dest col byte (linear)
  const int scol = ((tid & 3) * 8) ^ (((r0 >> 1) & 3) * 8);      // swizzled src col (same for r0+64)

  // frag read col (both-sides swizzle, thread-constant XOR)
  const int acol = (lg * 16) ^ (((lr >> 1) & 3) * 16);

  f32x4 acc[4][4] = {};
  for (int kt = 0; kt < K; kt += 32) {
    GLDS16(Aa + (size_t)(m0 + r0) * K + kt + scol,      (char*)L + r0 * 64 + cdb);
    GLDS16(Aa + (size_t)(m0 + r0 + 64) * K + kt + scol, (char*)L + (r0 + 64) * 64 + cdb);
    GLDS16(Bb + (size_t)(n0 + r0) * K + kt + scol,      (char*)L + 8192 + r0 * 64 + cdb);
    GLDS16(Bb + (size_t)(n0 + r0 + 64) * K + kt + scol, (char*)L + 8192 + (r0 + 64) * 64 + cdb);
    __syncthreads();
    bf16x8 a[4], b[4];
#pragma unroll
    for (int i = 0; i < 4; ++i) a[i] = *(const bf16x8*)((const char*)L + (wm * 64 + i * 16 + lr) * 64 + acol);
#pragma unroll
    for (int j = 0; j < 4; ++j) b[j] = *(const bf16x8*)((const char*)L + 8192 + (wn * 64 + j * 16 + lr) * 64 + acol);
#pragma unroll
    for (int i = 0; i < 4; ++i)
#pragma unroll
      for (int j = 0; j < 4; ++j)
        acc[i][j] = __builtin_amdgcn_mfma_f32_16x16x32_bf16(a[i], b[j], acc[i][j], 0, 0, 0);
    __syncthreads();
  }

  // ---- epilogue (wave tile 64x64: col = n0+wn*64+j*16+lr, row = m0+wm*64+i*16+lg*4+e)
  if (EPI == 1) {
    // fc1 swapped: C row = h, col = tok; pack 4 consecutive h
#pragma unroll
    for (int i = 0; i < 4; ++i) {
      const int h0 = m0 + wm * 64 + i * 16 + lg * 4;
      const float4 bi = *(const float4*)(bias + h0);
#pragma unroll
      for (int j = 0; j < 4; ++j) {
        const int tok = n0 + wn * 64 + j * 16 + lr;
        s16x4 o;
        o[0] = f2bf(gelu_fast(acc[i][j][0] + bi.x));
        o[1] = f2bf(gelu_fast(acc[i][j][1] + bi.y));
        o[2] = f2bf(gelu_fast(acc[i][j][2] + bi.z));
        o[3] = f2bf(gelu_fast(acc[i][j][3] + bi.w));
        *(s16x4*)(outh + (size_t)tok * 2048 + h0) = o;
      }
    }
  } else if (EPI == 0) {
#pragma unroll
    for (int j = 0; j < 4; ++j) {
      const int col = n0 + wn * 64 + j * 16 + lr;
      const float bc = bias[col];
#pragma unroll
      for (int i = 0; i < 4; ++i)
#pragma unroll
        for (int e = 0; e < 4; ++e) {
          const int row = m0 + wm * 64 + i * 16 + lg * 4 + e;
          float v = acc[i][j][e] + bc;
          const int wv = row >> 6, n = row & 63;
          const int bb = wv >> 6, wi = wv & 63;
          const int hs = (wi >> 3) * 8 + (n >> 3), ws2 = (wi & 7) * 8 + (n & 7);
          const int hh = (hs + 4) & 63, wwp = (ws2 + 4) & 63;
          const size_t orow = (size_t)bb * 4096 + hh * 64 + wwp;
          outf[orow * 512 + col] = resid[orow * 512 + col] + v;
        }
    }
  } else if (EPI == 2) {
#pragma unroll
    for (int j = 0; j < 4; ++j) {
      const int col = n0 + wn * 64 + j * 16 + lr;
      const float bc = bias[col];
#pragma unroll
      for (int i = 0; i < 4; ++i)
#pragma unroll
        for (int e = 0; e < 4; ++e) {
          const int row = m0 + wm * 64 + i * 16 + lg * 4 + e;
          outf[(size_t)row * 512 + col] = acc[i][j][e] + bc + resid[(size_t)row * 512 + col];
        }
    }
  } else {
    // qkv: seg uniform per block (n-tile of 128 never straddles a 512-col segment)
    const int seg = n0 >> 9;
#pragma unroll
    for (int j = 0; j < 4; ++j) {
      const int col = n0 + wn * 64 + j * 16 + lr;
      const float bc = bias[col];
#pragma unroll
      for (int i = 0; i < 4; ++i) {
        const int row0 = m0 + wm * 64 + i * 16 + lg * 4;
        if (seg == 2) {
          const int cc = col - 1024;                 // V^T packed 8B store
          s16x4 o;
#pragma unroll
          for (int e = 0; e < 4; ++e) o[e] = f2bf(acc[i][j][e] + bc);
          *(s16x4*)(outh + 67108864 +
                    (size_t)((row0 >> 6) * 16 + (cc >> 5)) * 2048 + (cc & 31) * 64 + (row0 & 63)) = o;
        } else {
#pragma unroll
          for (int e = 0; e < 4; ++e) {
            const int row = row0 + e;
            float v = acc[i][j][e] + bc;
            if (seg == 0) outh[(size_t)row * 512 + col] = f2bf(v * 0.17677669529663687f);
            else          outh[33554432 + (size_t)row * 512 + (col - 512)] = f2bf(v);
          }
        }
      }
    }
  }
}

// ---------------------------------------------------------------- launch
extern "C" void kernel_launch(void* const* d_in, const int* in_sizes, int n_in,
                              void* d_out, int out_size, void* d_ws, size_t ws_size,
                              hipStream_t stream) {
  (void)in_sizes; (void)n_in; (void)out_size; (void)ws_size;
  const float* x      = (const float*)d_in[0];
  const float* g1     = (const float*)d_in[1];
  const float* b1     = (const float*)d_in[2];
  const float* qkv_w  = (const float*)d_in[3];
  const float* qkv_b  = (const float*)d_in[4];
  const float* proj_w = (const float*)d_in[5];
  const float* proj_b = (const float*)d_in[6];
  const float* rpb    = (const float*)d_in[7];
  const float* g2     = (const float*)d_in[8];
  const float* b2     = (const float*)d_in[9];
  const float* fc1_w  = (const float*)d_in[10];
  const float* fc1_b  = (const float*)d_in[11];
  const float* fc2_w  = (const float*)d_in[12];
  const float* fc2_b  = (const float*)d_in[13];
  float* out = (float*)d_out;
  char* ws = (char*)d_ws;

  short* WQKVT  = (short*)(ws);                 // [1536][512] bf16   1.5MB
  short* WPROJT = (short*)(ws + 1572864);       // [512][512]         0.5MB
  short* WFC1T  = (short*)(ws + 2097152);       // [2048][512]        2MB
  short* WFC2T  = (short*)(ws + 4194304);       // [512][2048]        2MB
  float* X2     = (float*)(ws + 6291456);       // [65536][512] fp32  134MB
  float* BIASF  = (float*)(ws + 6291456);       // 256KB alias (dead before proj)
  short* ATT    = (short*)(ws + 140509184);     // [65536][512] bf16  64MB (X2N reuse)
  short* XW     = (short*)(ws + 207618048);     // [65536][512] bf16  64MB
  short* QB     = (short*)(ws + 274726912);     // Q|K|VT 3x64MB
  short* H1     = XW;                           // [65536][2048] bf16 256MB over XW+QB (dead)
  short* X2N    = ATT;

  transpose_bf16<<<3072, 256, 0, stream>>>(qkv_w,  WQKVT, 512, 1536);
  transpose_bf16<<<1024, 256, 0, stream>>>(proj_w, WPROJT, 512, 512);
  transpose_bf16<<<4096, 256, 0, stream>>>(fc1_w,  WFC1T, 512, 2048);
  transpose_bf16<<<4096, 256, 0, stream>>>(fc2_w,  WFC2T, 2048, 512);
  bias_expand<<<256, 256, 0, stream>>>(rpb, BIASF);

  ln_kernel<1><<<16384, 256, 0, stream>>>(x, g1, b1, XW);
  // qkv: A=XW [65536][512], BT=WQKVT [1536][512] -> Q|K|VT. grid 512x12
  gemm128v5<3, 512, 12><<<6144, 256, 0, stream>>>(XW, WQKVT, qkv_b, nullptr, nullptr, QB);
  attn_core<<<4096, 256, 0, stream>>>(QB, QB + 33554432, QB + 67108864, BIASF, ATT);
  // proj: A=ATT, BT=WPROJT -> X2 (window-reverse + x resid). grid 512x4
  gemm128v5<0, 512, 4><<<2048, 256, 0, stream>>>(ATT, WPROJT, proj_b, x, X2, nullptr);
  ln_kernel<0><<<16384, 256, 0, stream>>>(X2, g2, b2, X2N);
  // fc1 swapped: A=W1T [2048][512] (16 m-tiles, x-fastest), B=X2N -> H1[tok][2048]
  gemm128v5<1, 512, 16><<<8192, 256, 0, stream>>>(WFC1T, X2N, fc1_b, nullptr, nullptr, H1);
  // fc2: A=H1 [65536][2048], BT=W2T [512][2048] -> out + bias + X2 resid. grid 512x4
  gemm128v5<2, 2048, 4><<<2048, 256, 0, stream>>>(H1, WFC2T, fc2_b, X2, out, nullptr);
}

// Round 16
// 901.707 us; speedup vs baseline: 1.0166x; 1.0166x over previous
//
#include <hip/hip_runtime.h>
#include <hip/hip_bf16.h>

using f32x4  = __attribute__((ext_vector_type(4))) float;
using bf16x8 = __attribute__((ext_vector_type(8))) short;
using short8 = __attribute__((ext_vector_type(8))) short;
using s16x4  = __attribute__((ext_vector_type(4))) short;

#define DEVINL __device__ __forceinline__

DEVINL short f2bf(float f) {
  unsigned u = __builtin_bit_cast(unsigned, f);
  u += 0x7fffu + ((u >> 16) & 1u);          // RNE
  return (short)(u >> 16);
}

// tanh-approx GELU in sigmoid form: 0.5v(1+tanh(u)) == v/(1+exp(-2u))
DEVINL float gelu_fast(float v) {
  float t = __expf(-1.5957691216057308f * (v + 0.044715f * v * v * v));
  return v * __builtin_amdgcn_rcpf(1.0f + t);
}

#define GLDS16(g, l) __builtin_amdgcn_global_load_lds( \
    (const __attribute__((address_space(1))) void*)(g), \
    (__attribute__((address_space(3))) void*)(l), 16, 0, 0)

// ---------------------------------------------------------------- transpose
__global__ __launch_bounds__(256)
void transpose_bf16(const float* __restrict__ in, short* __restrict__ out, int R, int C) {
  int idx = blockIdx.x * 256 + threadIdx.x;
  if (idx >= R * C) return;
  int c = idx / R, r = idx % R;
  out[idx] = f2bf(in[(size_t)r * C + c]);
}

// ---------------------------------------------------------------- bias expand
__global__ __launch_bounds__(256)
void bias_expand(const float* __restrict__ rpb, float* __restrict__ BIASF) {
  int idx = blockIdx.x * 256 + threadIdx.x;   // 65536
  int head = idx >> 12, n = (idx >> 6) & 63, m = idx & 63;
  int i1 = n >> 3, j1 = n & 7, i2 = m >> 3, j2 = m & 7;
  BIASF[idx] = rpb[((i1 - i2 + 7) * 15 + (j1 - j2 + 7)) * 16 + head];
}

// ---------------------------------------------------------------- LayerNorm
template<int REMAP>
__global__ __launch_bounds__(256)
void ln_kernel(const float* __restrict__ X, const float* __restrict__ gamma,
               const float* __restrict__ beta, short* __restrict__ OUT) {
  const int lane = threadIdx.x & 63;
  const int wid  = threadIdx.x >> 6;
  const int t    = blockIdx.x * 4 + wid;
  const float* xp = X + (size_t)t * 512 + lane * 8;
  float4 a = *(const float4*)xp;
  float4 b = *(const float4*)(xp + 4);
  float s = a.x + a.y + a.z + a.w + b.x + b.y + b.z + b.w;
  float q = a.x*a.x + a.y*a.y + a.z*a.z + a.w*a.w
          + b.x*b.x + b.y*b.y + b.z*b.z + b.w*b.w;
#pragma unroll
  for (int d = 1; d < 64; d <<= 1) { s += __shfl_xor(s, d); q += __shfl_xor(q, d); }
  float mean = s * (1.0f / 512.0f);
  float var  = q * (1.0f / 512.0f) - mean * mean;
  float rstd = rsqrtf(var + 1e-5f);
  float4 g0 = *(const float4*)(gamma + lane * 8);
  float4 g1 = *(const float4*)(gamma + lane * 8 + 4);
  float4 b0 = *(const float4*)(beta + lane * 8);
  float4 b1 = *(const float4*)(beta + lane * 8 + 4);
  short8 o;
  o[0] = f2bf((a.x - mean) * rstd * g0.x + b0.x);
  o[1] = f2bf((a.y - mean) * rstd * g0.y + b0.y);
  o[2] = f2bf((a.z - mean) * rstd * g0.z + b0.z);
  o[3] = f2bf((a.w - mean) * rstd * g0.w + b0.w);
  o[4] = f2bf((b.x - mean) * rstd * g1.x + b1.x);
  o[5] = f2bf((b.y - mean) * rstd * g1.y + b1.y);
  o[6] = f2bf((b.z - mean) * rstd * g1.z + b1.z);
  o[7] = f2bf((b.w - mean) * rstd * g1.w + b1.w);
  size_t orow;
  if (REMAP) {
    int bb = t >> 12, l = t & 4095, hh = l >> 6, ww = l & 63;
    int hs = (hh + 60) & 63, ws2 = (ww + 60) & 63;   // (coord - 4) mod 64
    orow = (size_t)(bb * 64 + (hs >> 3) * 8 + (ws2 >> 3)) * 64 + (hs & 7) * 8 + (ws2 & 7);
  } else {
    orow = (size_t)t;
  }
  *(short8*)(OUT + orow * 512 + lane * 8) = o;
}

// ---------------------------------------------------------------- attention core
__global__ __launch_bounds__(256)
void attn_core(const short* __restrict__ Q, const short* __restrict__ Kb,
               const short* __restrict__ VT, const float* __restrict__ BIASF,
               short* __restrict__ AOUT) {
  __shared__ short P[4][4096];
  const int tid = threadIdx.x, lane = tid & 63, wid = tid >> 6;
  const int lr = lane & 15, lg = lane >> 4;
  const int gw = blockIdx.x * 4 + wid;
  const int win = gw >> 4, head = gw & 15;
  const int wimg = win & 63, wh = wimg >> 3, ww = wimg & 7;
  const size_t qbase = (size_t)win * 64 * 512 + head * 32;
  short* Pb = P[wid];

  bf16x8 aq[4], bk[4];
#pragma unroll
  for (int tm = 0; tm < 4; ++tm) aq[tm] = *(const bf16x8*)(Q  + qbase + (size_t)(tm * 16 + lr) * 512 + lg * 8);
#pragma unroll
  for (int tn = 0; tn < 4; ++tn) bk[tn] = *(const bf16x8*)(Kb + qbase + (size_t)(tn * 16 + lr) * 512 + lg * 8);
  f32x4 sa[4][4] = {};
#pragma unroll
  for (int tm = 0; tm < 4; ++tm)
#pragma unroll
    for (int tn = 0; tn < 4; ++tn)
      sa[tm][tn] = __builtin_amdgcn_mfma_f32_16x16x32_bf16(aq[tm], bk[tn], sa[tm][tn], 0, 0, 0);

  const float* bias_h = BIASF + head * 4096;
  float inv[4][4];
#pragma unroll
  for (int tm = 0; tm < 4; ++tm) {
#pragma unroll
    for (int e = 0; e < 4; ++e) {
      const int n = tm * 16 + lg * 4 + e;
      const int i1 = n >> 3, j1 = n & 7;
      const int rh1 = (wh == 7) ? 1 + (i1 >> 2) : 0;
      const int rw1 = (ww == 7) ? 1 + (j1 >> 2) : 0;
      float v[4];
      float mx = -3.0e38f;
#pragma unroll
      for (int tn = 0; tn < 4; ++tn) {
        const int m = tn * 16 + lr;
        const int mi = (m >> 3), mj = m & 7;
        const int rh2 = (wh == 7) ? 1 + (mi >> 2) : 0;
        const int rw2 = (ww == 7) ? 1 + (mj >> 2) : 0;
        float val = sa[tm][tn][e] + bias_h[n * 64 + m]
                  + ((rh1 != rh2 || rw1 != rw2) ? -100.0f : 0.0f);
        v[tn] = val;
        mx = fmaxf(mx, val);
      }
#pragma unroll
      for (int d = 1; d < 16; d <<= 1) mx = fmaxf(mx, __shfl_xor(mx, d));
      float sum = 0.f;
#pragma unroll
      for (int tn = 0; tn < 4; ++tn) { v[tn] = __expf(v[tn] - mx); sum += v[tn]; }
#pragma unroll
      for (int d = 1; d < 16; d <<= 1) sum += __shfl_xor(sum, d);
      inv[tm][e] = 1.0f / sum;
      const int sw = (n & 7) << 3;
#pragma unroll
      for (int tn = 0; tn < 4; ++tn) Pb[n * 64 + ((tn * 16 + lr) ^ sw)] = f2bf(v[tn]);
    }
  }
  __syncthreads();

  f32x4 oa[4][2] = {};
  const short* vt = VT + (size_t)win * 32768 + head * 2048;
#pragma unroll
  for (int ks = 0; ks < 2; ++ks) {
    bf16x8 pa[4], bv[2];
#pragma unroll
    for (int tm = 0; tm < 4; ++tm) {
      const int r = tm * 16 + lr;
      pa[tm] = *(const bf16x8*)(Pb + r * 64 + ((ks * 32 + lg * 8) ^ ((r & 7) << 3)));
    }
#pragma unroll
    for (int t2 = 0; t2 < 2; ++t2) bv[t2] = *(const bf16x8*)(vt + (t2 * 16 + lr) * 64 + ks * 32 + lg * 8);
#pragma unroll
    for (int tm = 0; tm < 4; ++tm)
#pragma unroll
      for (int t2 = 0; t2 < 2; ++t2)
        oa[tm][t2] = __builtin_amdgcn_mfma_f32_16x16x32_bf16(pa[tm], bv[t2], oa[tm][t2], 0, 0, 0);
  }
#pragma unroll
  for (int tm = 0; tm < 4; ++tm)
#pragma unroll
    for (int t2 = 0; t2 < 2; ++t2)
#pragma unroll
      for (int e = 0; e < 4; ++e) {
        const int n = tm * 16 + lg * 4 + e;
        AOUT[((size_t)win * 64 + n) * 512 + head * 32 + t2 * 16 + lr] = f2bf(oa[tm][t2][e] * inv[tm][e]);
      }
}

// ---------------------------------------------------------------- 256x128 GEMM (intensity-tile)
// M-tile 256, N-tile 128, BK=32, 8 waves (4m x 2n), wave tile 64x64 (acc 64
// regs/thread, same as 128^2). Per K-tile: 2.1 MFLOP / 24 KB staged = 87 F/B
// (vs 64 F/B at 128^2 — the L2-staging balance point measured R8-R15).
// v5-simple structure: single LDS buffer, 2 barriers/K-tile, compiler waitcnts,
// both-sides swizzle (0 conflicts), XCD-bijective block swizzle.
// Staging: 3 GLDS16/thread (A rows r, r+128; B row r), one shared swizzled col
// (valid since 128 % 4 == 0 in the (row>>1)&3 XOR term).
template<int EPI, int K, int NX>
__global__ __launch_bounds__(512, 1)
void gemm256x128(const short* __restrict__ Aa, const short* __restrict__ Bb,
                 const float* __restrict__ bias, const float* __restrict__ resid,
                 float* __restrict__ outf, short* __restrict__ outh) {
  __shared__ short L[(256 + 128) * 32];   // A: 0..16383 (256x64B), B: 16384..24575
  const int tid = threadIdx.x;
  const int lane = tid & 63, wid = tid >> 6;
  const int lr = lane & 15, lg = lane >> 4;
  const int wm = wid >> 1, wn = wid & 1;

  // XCD-aware bijective swizzle (all grids are multiples of 8)
  const int nwg = gridDim.x;
  const int id = blockIdx.x;
  const int id2 = (id & 7) * (nwg >> 3) + (id >> 3);
  const int mt    = (EPI == 1) ? (id2 % NX) : (id2 / NX);
  const int ntile = (EPI == 1) ? (id2 / NX) : (id2 % NX);
  const int m0 = mt * 256, n0 = ntile * 128;

  // staging: thread covers A rows r, r+128 and B row r (3 GLDS16)
  const int r0 = tid >> 2;                                       // 0..127
  const int cdb = (tid & 3) * 16;                                // dest col byte (linear)
  const int scol = ((tid & 3) * 8) ^ (((r0 >> 1) & 3) * 8);      // swizzled src col (r0, r0+128 agree)

  // frag read col (both-sides swizzle, thread-constant XOR)
  const int acol = (lg * 16) ^ (((lr >> 1) & 3) * 16);

  f32x4 acc[4][4] = {};
  for (int kt = 0; kt < K; kt += 32) {
    GLDS16(Aa + (size_t)(m0 + r0) * K + kt + scol,       (char*)L + r0 * 64 + cdb);
    GLDS16(Aa + (size_t)(m0 + r0 + 128) * K + kt + scol, (char*)L + (r0 + 128) * 64 + cdb);
    GLDS16(Bb + (size_t)(n0 + r0) * K + kt + scol,       (char*)L + 16384 + r0 * 64 + cdb);
    __syncthreads();
    bf16x8 a[4], b[4];
#pragma unroll
    for (int i = 0; i < 4; ++i) a[i] = *(const bf16x8*)((const char*)L + (wm * 64 + i * 16 + lr) * 64 + acol);
#pragma unroll
    for (int j = 0; j < 4; ++j) b[j] = *(const bf16x8*)((const char*)L + 16384 + (wn * 64 + j * 16 + lr) * 64 + acol);
#pragma unroll
    for (int i = 0; i < 4; ++i)
#pragma unroll
      for (int j = 0; j < 4; ++j)
        acc[i][j] = __builtin_amdgcn_mfma_f32_16x16x32_bf16(a[i], b[j], acc[i][j], 0, 0, 0);
    __syncthreads();
  }

  // ---- epilogue (col = n0+wn*64+j*16+lr, row = m0+wm*64+i*16+lg*4+e)
  if (EPI == 1) {
    // fc1 swapped: C row = h, col = tok; pack 4 consecutive h
#pragma unroll
    for (int i = 0; i < 4; ++i) {
      const int h0 = m0 + wm * 64 + i * 16 + lg * 4;
      const float4 bi = *(const float4*)(bias + h0);
#pragma unroll
      for (int j = 0; j < 4; ++j) {
        const int tok = n0 + wn * 64 + j * 16 + lr;
        s16x4 o;
        o[0] = f2bf(gelu_fast(acc[i][j][0] + bi.x));
        o[1] = f2bf(gelu_fast(acc[i][j][1] + bi.y));
        o[2] = f2bf(gelu_fast(acc[i][j][2] + bi.z));
        o[3] = f2bf(gelu_fast(acc[i][j][3] + bi.w));
        *(s16x4*)(outh + (size_t)tok * 2048 + h0) = o;
      }
    }
  } else if (EPI == 0) {
#pragma unroll
    for (int j = 0; j < 4; ++j) {
      const int col = n0 + wn * 64 + j * 16 + lr;
      const float bc = bias[col];
#pragma unroll
      for (int i = 0; i < 4; ++i)
#pragma unroll
        for (int e = 0; e < 4; ++e) {
          const int row = m0 + wm * 64 + i * 16 + lg * 4 + e;
          float v = acc[i][j][e] + bc;
          const int wv = row >> 6, n = row & 63;
          const int bb = wv >> 6, wi = wv & 63;
          const int hs = (wi >> 3) * 8 + (n >> 3), ws2 = (wi & 7) * 8 + (n & 7);
          const int hh = (hs + 4) & 63, wwp = (ws2 + 4) & 63;
          const size_t orow = (size_t)bb * 4096 + hh * 64 + wwp;
          outf[orow * 512 + col] = resid[orow * 512 + col] + v;
        }
    }
  } else if (EPI == 2) {
#pragma unroll
    for (int j = 0; j < 4; ++j) {
      const int col = n0 + wn * 64 + j * 16 + lr;
      const float bc = bias[col];
#pragma unroll
      for (int i = 0; i < 4; ++i)
#pragma unroll
        for (int e = 0; e < 4; ++e) {
          const int row = m0 + wm * 64 + i * 16 + lg * 4 + e;
          outf[(size_t)row * 512 + col] = acc[i][j][e] + bc + resid[(size_t)row * 512 + col];
        }
    }
  } else {
    // qkv: seg uniform per block (n-tile of 128 never straddles a 512-col segment)
    const int seg = n0 >> 9;
#pragma unroll
    for (int j = 0; j < 4; ++j) {
      const int col = n0 + wn * 64 + j * 16 + lr;
      const float bc = bias[col];
#pragma unroll
      for (int i = 0; i < 4; ++i) {
        const int row0 = m0 + wm * 64 + i * 16 + lg * 4;
        if (seg == 2) {
          const int cc = col - 1024;                 // V^T packed 8B store
          s16x4 o;
#pragma unroll
          for (int e = 0; e < 4; ++e) o[e] = f2bf(acc[i][j][e] + bc);
          *(s16x4*)(outh + 67108864 +
                    (size_t)((row0 >> 6) * 16 + (cc >> 5)) * 2048 + (cc & 31) * 64 + (row0 & 63)) = o;
        } else {
#pragma unroll
          for (int e = 0; e < 4; ++e) {
            const int row = row0 + e;
            float v = acc[i][j][e] + bc;
            if (seg == 0) outh[(size_t)row * 512 + col] = f2bf(v * 0.17677669529663687f);
            else          outh[33554432 + (size_t)row * 512 + (col - 512)] = f2bf(v);
          }
        }
      }
    }
  }
}

// ---------------------------------------------------------------- launch
extern "C" void kernel_launch(void* const* d_in, const int* in_sizes, int n_in,
                              void* d_out, int out_size, void* d_ws, size_t ws_size,
                              hipStream_t stream) {
  (void)in_sizes; (void)n_in; (void)out_size; (void)ws_size;
  const float* x      = (const float*)d_in[0];
  const float* g1     = (const float*)d_in[1];
  const float* b1     = (const float*)d_in[2];
  const float* qkv_w  = (const float*)d_in[3];
  const float* qkv_b  = (const float*)d_in[4];
  const float* proj_w = (const float*)d_in[5];
  const float* proj_b = (const float*)d_in[6];
  const float* rpb    = (const float*)d_in[7];
  const float* g2     = (const float*)d_in[8];
  const float* b2     = (const float*)d_in[9];
  const float* fc1_w  = (const float*)d_in[10];
  const float* fc1_b  = (const float*)d_in[11];
  const float* fc2_w  = (const float*)d_in[12];
  const float* fc2_b  = (const float*)d_in[13];
  float* out = (float*)d_out;
  char* ws = (char*)d_ws;

  short* WQKVT  = (short*)(ws);                 // [1536][512] bf16   1.5MB
  short* WPROJT = (short*)(ws + 1572864);       // [512][512]         0.5MB
  short* WFC1T  = (short*)(ws + 2097152);       // [2048][512]        2MB
  short* WFC2T  = (short*)(ws + 4194304);       // [512][2048]        2MB
  float* X2     = (float*)(ws + 6291456);       // [65536][512] fp32  134MB
  float* BIASF  = (float*)(ws + 6291456);       // 256KB alias (dead before proj)
  short* ATT    = (short*)(ws + 140509184);     // [65536][512] bf16  64MB (X2N reuse)
  short* XW     = (short*)(ws + 207618048);     // [65536][512] bf16  64MB
  short* QB     = (short*)(ws + 274726912);     // Q|K|VT 3x64MB
  short* H1     = XW;                           // [65536][2048] bf16 256MB over XW+QB (dead)
  short* X2N    = ATT;

  transpose_bf16<<<3072, 256, 0, stream>>>(qkv_w,  WQKVT, 512, 1536);
  transpose_bf16<<<1024, 256, 0, stream>>>(proj_w, WPROJT, 512, 512);
  transpose_bf16<<<4096, 256, 0, stream>>>(fc1_w,  WFC1T, 512, 2048);
  transpose_bf16<<<4096, 256, 0, stream>>>(fc2_w,  WFC2T, 2048, 512);
  bias_expand<<<256, 256, 0, stream>>>(rpb, BIASF);

  ln_kernel<1><<<16384, 256, 0, stream>>>(x, g1, b1, XW);
  // qkv: A=XW [65536][512] (256 m-tiles), BT=WQKVT [1536][512] (12 n-tiles)
  gemm256x128<3, 512, 12><<<3072, 512, 0, stream>>>(XW, WQKVT, qkv_b, nullptr, nullptr, QB);
  attn_core<<<4096, 256, 0, stream>>>(QB, QB + 33554432, QB + 67108864, BIASF, ATT);
  // proj: A=ATT (256 m-tiles), BT=WPROJT (4 n-tiles) -> X2 (window-reverse + x resid)
  gemm256x128<0, 512, 4><<<1024, 512, 0, stream>>>(ATT, WPROJT, proj_b, x, X2, nullptr);
  ln_kernel<0><<<16384, 256, 0, stream>>>(X2, g2, b2, X2N);
  // fc1 swapped: A=W1T [2048][512] (8 m-tiles), B=X2N (512 n-tiles) -> H1[tok][2048]
  gemm256x128<1, 512, 8><<<4096, 512, 0, stream>>>(WFC1T, X2N, fc1_b, nullptr, nullptr, H1);
  // fc2: A=H1 [65536][2048] (256 m-tiles), BT=W2T (4 n-tiles) -> out + bias + X2 resid
  gemm256x128<2, 2048, 4><<<1024, 512, 0, stream>>>(H1, WFC2T, fc2_b, X2, out, nullptr);
}

// Round 17
// 843.123 us; speedup vs baseline: 1.0873x; 1.0695x over previous
//
#include <hip/hip_runtime.h>
#include <hip/hip_bf16.h>

using f32x4  = __attribute__((ext_vector_type(4))) float;
using bf16x8 = __attribute__((ext_vector_type(8))) short;
using short8 = __attribute__((ext_vector_type(8))) short;
using s16x4  = __attribute__((ext_vector_type(4))) short;

#define DEVINL __device__ __forceinline__

DEVINL short f2bf(float f) {
  unsigned u = __builtin_bit_cast(unsigned, f);
  u += 0x7fffu + ((u >> 16) & 1u);          // RNE
  return (short)(u >> 16);
}

// tanh-approx GELU in sigmoid form: 0.5v(1+tanh(u)) == v/(1+exp(-2u))
DEVINL float gelu_fast(float v) {
  float t = __expf(-1.5957691216057308f * (v + 0.044715f * v * v * v));
  return v * __builtin_amdgcn_rcpf(1.0f + t);
}

#define GLDS16(g, l) __builtin_amdgcn_global_load_lds( \
    (const __attribute__((address_space(1))) void*)(g), \
    (__attribute__((address_space(3))) void*)(l), 16, 0, 0)

// ---------------------------------------------------------------- transpose
__global__ __launch_bounds__(256)
void transpose_bf16(const float* __restrict__ in, short* __restrict__ out, int R, int C) {
  int idx = blockIdx.x * 256 + threadIdx.x;
  if (idx >= R * C) return;
  int c = idx / R, r = idx % R;
  out[idx] = f2bf(in[(size_t)r * C + c]);
}

// ---------------------------------------------------------------- bias expand
__global__ __launch_bounds__(256)
void bias_expand(const float* __restrict__ rpb, float* __restrict__ BIASF) {
  int idx = blockIdx.x * 256 + threadIdx.x;   // 65536
  int head = idx >> 12, n = (idx >> 6) & 63, m = idx & 63;
  int i1 = n >> 3, j1 = n & 7, i2 = m >> 3, j2 = m & 7;
  BIASF[idx] = rpb[((i1 - i2 + 7) * 15 + (j1 - j2 + 7)) * 16 + head];
}

// ---------------------------------------------------------------- LayerNorm
template<int REMAP>
__global__ __launch_bounds__(256)
void ln_kernel(const float* __restrict__ X, const float* __restrict__ gamma,
               const float* __restrict__ beta, short* __restrict__ OUT) {
  const int lane = threadIdx.x & 63;
  const int wid  = threadIdx.x >> 6;
  const int t    = blockIdx.x * 4 + wid;
  const float* xp = X + (size_t)t * 512 + lane * 8;
  float4 a = *(const float4*)xp;
  float4 b = *(const float4*)(xp + 4);
  float s = a.x + a.y + a.z + a.w + b.x + b.y + b.z + b.w;
  float q = a.x*a.x + a.y*a.y + a.z*a.z + a.w*a.w
          + b.x*b.x + b.y*b.y + b.z*b.z + b.w*b.w;
#pragma unroll
  for (int d = 1; d < 64; d <<= 1) { s += __shfl_xor(s, d); q += __shfl_xor(q, d); }
  float mean = s * (1.0f / 512.0f);
  float var  = q * (1.0f / 512.0f) - mean * mean;
  float rstd = rsqrtf(var + 1e-5f);
  float4 g0 = *(const float4*)(gamma + lane * 8);
  float4 g1 = *(const float4*)(gamma + lane * 8 + 4);
  float4 b0 = *(const float4*)(beta + lane * 8);
  float4 b1 = *(const float4*)(beta + lane * 8 + 4);
  short8 o;
  o[0] = f2bf((a.x - mean) * rstd * g0.x + b0.x);
  o[1] = f2bf((a.y - mean) * rstd * g0.y + b0.y);
  o[2] = f2bf((a.z - mean) * rstd * g0.z + b0.z);
  o[3] = f2bf((a.w - mean) * rstd * g0.w + b0.w);
  o[4] = f2bf((b.x - mean) * rstd * g1.x + b1.x);
  o[5] = f2bf((b.y - mean) * rstd * g1.y + b1.y);
  o[6] = f2bf((b.z - mean) * rstd * g1.z + b1.z);
  o[7] = f2bf((b.w - mean) * rstd * g1.w + b1.w);
  size_t orow;
  if (REMAP) {
    int bb = t >> 12, l = t & 4095, hh = l >> 6, ww = l & 63;
    int hs = (hh + 60) & 63, ws2 = (ww + 60) & 63;   // (coord - 4) mod 64
    orow = (size_t)(bb * 64 + (hs >> 3) * 8 + (ws2 >> 3)) * 64 + (hs & 7) * 8 + (ws2 & 7);
  } else {
    orow = (size_t)t;
  }
  *(short8*)(OUT + orow * 512 + lane * 8) = o;
}

// ---------------------------------------------------------------- attention core
__global__ __launch_bounds__(256)
void attn_core(const short* __restrict__ Q, const short* __restrict__ Kb,
               const short* __restrict__ VT, const float* __restrict__ BIASF,
               short* __restrict__ AOUT) {
  __shared__ short P[4][4096];
  const int tid = threadIdx.x, lane = tid & 63, wid = tid >> 6;
  const int lr = lane & 15, lg = lane >> 4;
  const int gw = blockIdx.x * 4 + wid;
  const int win = gw >> 4, head = gw & 15;
  const int wimg = win & 63, wh = wimg >> 3, ww = wimg & 7;
  const size_t qbase = (size_t)win * 64 * 512 + head * 32;
  short* Pb = P[wid];

  bf16x8 aq[4], bk[4];
#pragma unroll
  for (int tm = 0; tm < 4; ++tm) aq[tm] = *(const bf16x8*)(Q  + qbase + (size_t)(tm * 16 + lr) * 512 + lg * 8);
#pragma unroll
  for (int tn = 0; tn < 4; ++tn) bk[tn] = *(const bf16x8*)(Kb + qbase + (size_t)(tn * 16 + lr) * 512 + lg * 8);
  f32x4 sa[4][4] = {};
#pragma unroll
  for (int tm = 0; tm < 4; ++tm)
#pragma unroll
    for (int tn = 0; tn < 4; ++tn)
      sa[tm][tn] = __builtin_amdgcn_mfma_f32_16x16x32_bf16(aq[tm], bk[tn], sa[tm][tn], 0, 0, 0);

  const float* bias_h = BIASF + head * 4096;
  float inv[4][4];
#pragma unroll
  for (int tm = 0; tm < 4; ++tm) {
#pragma unroll
    for (int e = 0; e < 4; ++e) {
      const int n = tm * 16 + lg * 4 + e;
      const int i1 = n >> 3, j1 = n & 7;
      const int rh1 = (wh == 7) ? 1 + (i1 >> 2) : 0;
      const int rw1 = (ww == 7) ? 1 + (j1 >> 2) : 0;
      float v[4];
      float mx = -3.0e38f;
#pragma unroll
      for (int tn = 0; tn < 4; ++tn) {
        const int m = tn * 16 + lr;
        const int mi = (m >> 3), mj = m & 7;
        const int rh2 = (wh == 7) ? 1 + (mi >> 2) : 0;
        const int rw2 = (ww == 7) ? 1 + (mj >> 2) : 0;
        float val = sa[tm][tn][e] + bias_h[n * 64 + m]
                  + ((rh1 != rh2 || rw1 != rw2) ? -100.0f : 0.0f);
        v[tn] = val;
        mx = fmaxf(mx, val);
      }
#pragma unroll
      for (int d = 1; d < 16; d <<= 1) mx = fmaxf(mx, __shfl_xor(mx, d));
      float sum = 0.f;
#pragma unroll
      for (int tn = 0; tn < 4; ++tn) { v[tn] = __expf(v[tn] - mx); sum += v[tn]; }
#pragma unroll
      for (int d = 1; d < 16; d <<= 1) sum += __shfl_xor(sum, d);
      inv[tm][e] = 1.0f / sum;
      const int sw = (n & 7) << 3;
#pragma unroll
      for (int tn = 0; tn < 4; ++tn) Pb[n * 64 + ((tn * 16 + lr) ^ sw)] = f2bf(v[tn]);
    }
  }
  __syncthreads();

  f32x4 oa[4][2] = {};
  const short* vt = VT + (size_t)win * 32768 + head * 2048;
#pragma unroll
  for (int ks = 0; ks < 2; ++ks) {
    bf16x8 pa[4], bv[2];
#pragma unroll
    for (int tm = 0; tm < 4; ++tm) {
      const int r = tm * 16 + lr;
      pa[tm] = *(const bf16x8*)(Pb + r * 64 + ((ks * 32 + lg * 8) ^ ((r & 7) << 3)));
    }
#pragma unroll
    for (int t2 = 0; t2 < 2; ++t2) bv[t2] = *(const bf16x8*)(vt + (t2 * 16 + lr) * 64 + ks * 32 + lg * 8);
#pragma unroll
    for (int tm = 0; tm < 4; ++tm)
#pragma unroll
      for (int t2 = 0; t2 < 2; ++t2)
        oa[tm][t2] = __builtin_amdgcn_mfma_f32_16x16x32_bf16(pa[tm], bv[t2], oa[tm][t2], 0, 0, 0);
  }
#pragma unroll
  for (int tm = 0; tm < 4; ++tm)
#pragma unroll
    for (int t2 = 0; t2 < 2; ++t2)
#pragma unroll
      for (int e = 0; e < 4; ++e) {
        const int n = tm * 16 + lg * 4 + e;
        AOUT[((size_t)win * 64 + n) * 512 + head * 32 + t2 * 16 + lr] = f2bf(oa[tm][t2][e] * inv[tm][e]);
      }
}

// ---------------------------------------------------------------- 256x128 GEMM, BK=64
// Mechanism fix (R8-R16 plateau): per K-phase the vmcnt(0) drain (~600cy)
// dwarfed 16 MFMA/wave (~160cy issue/SIMD) -> util capped ~25%. BK=64 doubles
// MFMA per drain (32/wave) and halves barrier count. LDS 48KB (A 32K + B 16K)
// -> 2 blocks/CU; acc 64 + ~60 arch regs -> 16 waves/CU.
// Staging obeys global_load_lds HW rule (dest = uniform base + lane*16):
// instr c covers bytes c*8192 + tid*16 => row c*64 + (tid>>3), slot tid&7;
// source pre-swizzled slot^=(row&7) (= (tid&7)^((tid>>3)&7), thread-const);
// read uses same involution: slot = (kk*4+lg)^(lr&7). 2-way conflicts = free.
// 8 waves (4m x 2n), wave tile 64x64. Row stride in LDS = 128B.
template<int EPI, int K, int NX>
__global__ __launch_bounds__(512, 1)
void gemmBK64(const short* __restrict__ Aa, const short* __restrict__ Bb,
              const float* __restrict__ bias, const float* __restrict__ resid,
              float* __restrict__ outf, short* __restrict__ outh) {
  constexpr int NT = K / 64;
  __shared__ short L[24576];   // A bytes [0,32768), B bytes [32768,49152)
  const int tid = threadIdx.x;
  const int lane = tid & 63, wid = tid >> 6;
  const int lr = lane & 15, lg = lane >> 4;
  const int wm = wid >> 1, wn = wid & 1;

  // XCD-aware bijective swizzle (all grids are multiples of 8)
  const int nwg = gridDim.x;
  const int id = blockIdx.x;
  const int id2 = (id & 7) * (nwg >> 3) + (id >> 3);
  const int mt    = (EPI == 1) ? (id2 % NX) : (id2 / NX);
  const int ntile = (EPI == 1) ? (id2 / NX) : (id2 % NX);
  const int m0 = mt * 256, n0 = ntile * 128;

  // staging geometry: instr c -> row c*64 + rr, phys slot tid&7
  const int rr = tid >> 3;                                   // 0..63
  const int ss = ((tid & 7) ^ (rr & 7)) * 8;                 // swizzled source col (elems)
  const short* pA = Aa + (size_t)(m0 + rr) * K + ss;
  const short* pB = Bb + (size_t)(n0 + rr) * K + ss;
  char* Ld = (char*)L + tid * 16;

  // frag read bases (slot = (kk*4+lg)^(lr&7))
  const int xr = lr & 7;
  const char* rA0 = (char*)L + (wm * 64 + lr) * 128 + ((lg ^ xr) << 4);
  const char* rA1 = (char*)L + (wm * 64 + lr) * 128 + (((4 + lg) ^ xr) << 4);
  const char* rB0 = (char*)L + 32768 + (wn * 64 + lr) * 128 + ((lg ^ xr) << 4);
  const char* rB1 = (char*)L + 32768 + (wn * 64 + lr) * 128 + (((4 + lg) ^ xr) << 4);

  f32x4 acc[4][4] = {};
  for (int kt = 0; kt < NT; ++kt) {
    const int ko = kt * 64;
    GLDS16(pA + ko,                    Ld);
    GLDS16(pA + ko + (size_t)64  * K,  Ld + 8192);
    GLDS16(pA + ko + (size_t)128 * K,  Ld + 16384);
    GLDS16(pA + ko + (size_t)192 * K,  Ld + 24576);
    GLDS16(pB + ko,                    Ld + 32768);
    GLDS16(pB + ko + (size_t)64  * K,  Ld + 40960);
    __syncthreads();
    bf16x8 a[4], b[4];
#pragma unroll
    for (int i = 0; i < 4; ++i) a[i] = *(const bf16x8*)(rA0 + i * 2048);
#pragma unroll
    for (int j = 0; j < 4; ++j) b[j] = *(const bf16x8*)(rB0 + j * 2048);
#pragma unroll
    for (int i = 0; i < 4; ++i)
#pragma unroll
      for (int j = 0; j < 4; ++j)
        acc[i][j] = __builtin_amdgcn_mfma_f32_16x16x32_bf16(a[i], b[j], acc[i][j], 0, 0, 0);
#pragma unroll
    for (int i = 0; i < 4; ++i) a[i] = *(const bf16x8*)(rA1 + i * 2048);
#pragma unroll
    for (int j = 0; j < 4; ++j) b[j] = *(const bf16x8*)(rB1 + j * 2048);
#pragma unroll
    for (int i = 0; i < 4; ++i)
#pragma unroll
      for (int j = 0; j < 4; ++j)
        acc[i][j] = __builtin_amdgcn_mfma_f32_16x16x32_bf16(a[i], b[j], acc[i][j], 0, 0, 0);
    __syncthreads();
  }

  // ---- epilogue (col = n0+wn*64+j*16+lr, row = m0+wm*64+i*16+lg*4+e)
  if (EPI == 1) {
    // fc1 swapped: C row = h, col = tok; pack 4 consecutive h
#pragma unroll
    for (int i = 0; i < 4; ++i) {
      const int h0 = m0 + wm * 64 + i * 16 + lg * 4;
      const float4 bi = *(const float4*)(bias + h0);
#pragma unroll
      for (int j = 0; j < 4; ++j) {
        const int tok = n0 + wn * 64 + j * 16 + lr;
        s16x4 o;
        o[0] = f2bf(gelu_fast(acc[i][j][0] + bi.x));
        o[1] = f2bf(gelu_fast(acc[i][j][1] + bi.y));
        o[2] = f2bf(gelu_fast(acc[i][j][2] + bi.z));
        o[3] = f2bf(gelu_fast(acc[i][j][3] + bi.w));
        *(s16x4*)(outh + (size_t)tok * 2048 + h0) = o;
      }
    }
  } else if (EPI == 0) {
#pragma unroll
    for (int j = 0; j < 4; ++j) {
      const int col = n0 + wn * 64 + j * 16 + lr;
      const float bc = bias[col];
#pragma unroll
      for (int i = 0; i < 4; ++i)
#pragma unroll
        for (int e = 0; e < 4; ++e) {
          const int row = m0 + wm * 64 + i * 16 + lg * 4 + e;
          float v = acc[i][j][e] + bc;
          const int wv = row >> 6, n = row & 63;
          const int bb = wv >> 6, wi = wv & 63;
          const int hs = (wi >> 3) * 8 + (n >> 3), ws2 = (wi & 7) * 8 + (n & 7);
          const int hh = (hs + 4) & 63, wwp = (ws2 + 4) & 63;
          const size_t orow = (size_t)bb * 4096 + hh * 64 + wwp;
          outf[orow * 512 + col] = resid[orow * 512 + col] + v;
        }
    }
  } else if (EPI == 2) {
#pragma unroll
    for (int j = 0; j < 4; ++j) {
      const int col = n0 + wn * 64 + j * 16 + lr;
      const float bc = bias[col];
#pragma unroll
      for (int i = 0; i < 4; ++i)
#pragma unroll
        for (int e = 0; e < 4; ++e) {
          const int row = m0 + wm * 64 + i * 16 + lg * 4 + e;
          outf[(size_t)row * 512 + col] = acc[i][j][e] + bc + resid[(size_t)row * 512 + col];
        }
    }
  } else {
    // qkv: seg uniform per block (n-tile of 128 never straddles a 512-col segment)
    const int seg = n0 >> 9;
#pragma unroll
    for (int j = 0; j < 4; ++j) {
      const int col = n0 + wn * 64 + j * 16 + lr;
      const float bc = bias[col];
#pragma unroll
      for (int i = 0; i < 4; ++i) {
        const int row0 = m0 + wm * 64 + i * 16 + lg * 4;
        if (seg == 2) {
          const int cc = col - 1024;                 // V^T packed 8B store
          s16x4 o;
#pragma unroll
          for (int e = 0; e < 4; ++e) o[e] = f2bf(acc[i][j][e] + bc);
          *(s16x4*)(outh + 67108864 +
                    (size_t)((row0 >> 6) * 16 + (cc >> 5)) * 2048 + (cc & 31) * 64 + (row0 & 63)) = o;
        } else {
#pragma unroll
          for (int e = 0; e < 4; ++e) {
            const int row = row0 + e;
            float v = acc[i][j][e] + bc;
            if (seg == 0) outh[(size_t)row * 512 + col] = f2bf(v * 0.17677669529663687f);
            else          outh[33554432 + (size_t)row * 512 + (col - 512)] = f2bf(v);
          }
        }
      }
    }
  }
}

// ---------------------------------------------------------------- launch
extern "C" void kernel_launch(void* const* d_in, const int* in_sizes, int n_in,
                              void* d_out, int out_size, void* d_ws, size_t ws_size,
                              hipStream_t stream) {
  (void)in_sizes; (void)n_in; (void)out_size; (void)ws_size;
  const float* x      = (const float*)d_in[0];
  const float* g1     = (const float*)d_in[1];
  const float* b1     = (const float*)d_in[2];
  const float* qkv_w  = (const float*)d_in[3];
  const float* qkv_b  = (const float*)d_in[4];
  const float* proj_w = (const float*)d_in[5];
  const float* proj_b = (const float*)d_in[6];
  const float* rpb    = (const float*)d_in[7];
  const float* g2     = (const float*)d_in[8];
  const float* b2     = (const float*)d_in[9];
  const float* fc1_w  = (const float*)d_in[10];
  const float* fc1_b  = (const float*)d_in[11];
  const float* fc2_w  = (const float*)d_in[12];
  const float* fc2_b  = (const float*)d_in[13];
  float* out = (float*)d_out;
  char* ws = (char*)d_ws;

  short* WQKVT  = (short*)(ws);                 // [1536][512] bf16   1.5MB
  short* WPROJT = (short*)(ws + 1572864);       // [512][512]         0.5MB
  short* WFC1T  = (short*)(ws + 2097152);       // [2048][512]        2MB
  short* WFC2T  = (short*)(ws + 4194304);       // [512][2048]        2MB
  float* X2     = (float*)(ws + 6291456);       // [65536][512] fp32  134MB
  float* BIASF  = (float*)(ws + 6291456);       // 256KB alias (dead before proj)
  short* ATT    = (short*)(ws + 140509184);     // [65536][512] bf16  64MB (X2N reuse)
  short* XW     = (short*)(ws + 207618048);     // [65536][512] bf16  64MB
  short* QB     = (short*)(ws + 274726912);     // Q|K|VT 3x64MB
  short* H1     = XW;                           // [65536][2048] bf16 256MB over XW+QB (dead)
  short* X2N    = ATT;

  transpose_bf16<<<3072, 256, 0, stream>>>(qkv_w,  WQKVT, 512, 1536);
  transpose_bf16<<<1024, 256, 0, stream>>>(proj_w, WPROJT, 512, 512);
  transpose_bf16<<<4096, 256, 0, stream>>>(fc1_w,  WFC1T, 512, 2048);
  transpose_bf16<<<4096, 256, 0, stream>>>(fc2_w,  WFC2T, 2048, 512);
  bias_expand<<<256, 256, 0, stream>>>(rpb, BIASF);

  ln_kernel<1><<<16384, 256, 0, stream>>>(x, g1, b1, XW);
  // qkv: A=XW (256 m-tiles), BT=WQKVT (12 n-tiles)
  gemmBK64<3, 512, 12><<<3072, 512, 0, stream>>>(XW, WQKVT, qkv_b, nullptr, nullptr, QB);
  attn_core<<<4096, 256, 0, stream>>>(QB, QB + 33554432, QB + 67108864, BIASF, ATT);
  // proj: A=ATT (256 m-tiles), BT=WPROJT (4 n-tiles) -> X2 (window-reverse + x resid)
  gemmBK64<0, 512, 4><<<1024, 512, 0, stream>>>(ATT, WPROJT, proj_b, x, X2, nullptr);
  ln_kernel<0><<<16384, 256, 0, stream>>>(X2, g2, b2, X2N);
  // fc1 swapped: A=W1T (8 m-tiles), B=X2N (512 n-tiles) -> H1[tok][2048]
  gemmBK64<1, 512, 8><<<4096, 512, 0, stream>>>(WFC1T, X2N, fc1_b, nullptr, nullptr, H1);
  // fc2: A=H1 (256 m-tiles), BT=W2T (4 n-tiles) -> out + bias + X2 resid
  gemmBK64<2, 2048, 4><<<1024, 512, 0, stream>>>(H1, WFC2T, fc2_b, X2, out, nullptr);
}